// Round 7
// baseline (392.037 us; speedup 1.0000x reference)
//
#include <hip/hip_runtime.h>

// SIR RK4 trajectory: 500000 rows × 3 states × 50 timesteps, f32.
// Reference quirks replicated exactly:
//   - _sir_eq returns the NEW STATE (x + f(x)), not the derivative.
//   - new = x_ORIGINAL + STEP/6*(k1+2k2+2k3+k4)  (closure over x, not prev).
// Output layout: out[row*150 + t*3 + c].
//
// Round 7: two-chunk LDS staging for occupancy.
//   Round-6 post-mortem: full-trajectory staging (600 B/row -> 37.5 KiB/block)
//   capped occupancy at 4 single-wave blocks/CU = 1 wave/SIMD; the serial RK4
//   dep chain then runs latency-bound (~2-3x issue time), store-issue duty
//   cycle drops to ~6 B/cyc/CU < 10 B/cyc HBM rate -> kernel ~144 us, 3x over
//   the 48 us write floor. Fix: split trajectory into 26+24-step chunks,
//   LDS = 64 rows x 78 floats = 19.97 KiB -> 8 blocks/CU = 2 waves/SIMD.
//   Chunk writes are float2-aligned islands (312 B + 288 B per 600 B row);
//   ~2 split lines/row merge in L2 (same block writes both halves ~5 us
//   apart), worst case +20% write traffic -- cheap vs 2x latency hiding.

#define BATCH 500000
#define NT    50
#define NF    (NT * 3)     // 150 floats per row
#define S0    26           // chunk-0 timesteps (t = 0..25), 78 floats/row
#define S1    24           // chunk-1 timesteps (t = 26..49), 72 floats/row
#define ROWS  64           // rows per block == threads per block (1 wave)

struct F3 { float s, i, r; };

__device__ __forceinline__ F3 sir_eq(F3 v, float b, float g, float rn) {
    float inf = b * v.s * v.i * rn;
    float rec = g * v.i;
    F3 o;
    o.s = v.s - inf;
    o.i = v.i + inf - rec;
    o.r = v.r + rec;
    return o;
}

__device__ __forceinline__ F3 rk_step(F3 prev, F3 x0, float b, float g) {
    // _sir_eq preserves the component sum, so the four divisor sums are
    // n * {1, 1.05, 1.0525, 1.10525} -> 1 rcp + 3 muls (measured absmax
    // 0.0078 vs threshold 0.0259).
    float n  = prev.s + prev.i + prev.r;
    float r1 = __builtin_amdgcn_rcpf(n);
    float r2 = r1 * 0.952380952f;  // 1/1.05
    float r3 = r1 * 0.950118765f;  // 1/1.0525
    float r4 = r1 * 0.904772676f;  // 1/1.10525

    F3 k1 = sir_eq(prev, b, g, r1);
    F3 a2 = { fmaf(0.05f, k1.s, prev.s), fmaf(0.05f, k1.i, prev.i), fmaf(0.05f, k1.r, prev.r) };
    F3 k2 = sir_eq(a2, b, g, r2);
    F3 a3 = { fmaf(0.05f, k2.s, prev.s), fmaf(0.05f, k2.i, prev.i), fmaf(0.05f, k2.r, prev.r) };
    F3 k3 = sir_eq(a3, b, g, r3);
    F3 a4 = { fmaf(0.10f, k3.s, prev.s), fmaf(0.10f, k3.i, prev.i), fmaf(0.10f, k3.r, prev.r) };
    F3 k4 = sir_eq(a4, b, g, r4);

    const float C = (float)(0.1 / 6.0);
    F3 nw;
    nw.s = fmaf(C, (k1.s + k4.s) + 2.0f * (k2.s + k3.s), x0.s);
    nw.i = fmaf(C, (k1.i + k4.i) + 2.0f * (k2.i + k3.i), x0.i);
    nw.r = fmaf(C, (k1.r + k4.r) + 2.0f * (k2.r + k3.r), x0.r);
    return nw;
}

__global__ __launch_bounds__(ROWS) void sir_rk4_kernel(
        const float* __restrict__ x,
        const float* __restrict__ beta,
        const float* __restrict__ gamma,
        float* __restrict__ out) {
    // One buffer, reused by both chunks (chunk 1 uses stride 72 so the
    // float2 sweep index stays dense: lds float offset == 2*li).
    __shared__ __align__(16) float lds[ROWS * S0 * 3];   // 19968 B -> 8 blocks/CU

    const int lane  = threadIdx.x;
    const int row0  = blockIdx.x * ROWS;
    const int row   = row0 + lane;
    const int nrows = min(ROWS, BATCH - row0);
    const bool active = lane < nrows;

    const float b = beta[0];
    const float g = gamma[0];

    F3 xv = { 1.0f, 1.0f, 1.0f };                        // benign for tail lanes
    if (active) {
        xv.s = x[(size_t)row * 3 + 0];
        xv.i = x[(size_t)row * 3 + 1];
        xv.r = x[(size_t)row * 3 + 2];
    }

    // ---------------- chunk 0: t = 0..25 (78 floats/row) ----------------
    {
        float* myrow = lds + lane * (S0 * 3);
        myrow[0] = xv.s; myrow[1] = xv.i; myrow[2] = xv.r;   // t=0 is x
    }
    F3 prev = xv;
    for (int s = 1; s < S0; ++s) {
        prev = rk_step(prev, xv, b, g);
        float* myrow = lds + lane * (S0 * 3);
        myrow[s * 3 + 0] = prev.s;
        myrow[s * 3 + 1] = prev.i;
        myrow[s * 3 + 2] = prev.r;
    }
    __syncthreads();                                     // 1 wave: lgkmcnt drain

    {
        const float2* l2 = (const float2*)lds;
        const int per = S0 * 3 / 2;                      // 39 float2 per row
        const int total2 = nrows * per;
        for (int it = 0; it < per; ++it) {
            int li = it * ROWS + lane;
            if (li < total2) {
                int r  = li / per;
                int gg = li - r * per;
                // dst byte = 600*(row0+r) + 8*gg : 8B-aligned
                *reinterpret_cast<float2*>(
                    out + (size_t)(row0 + r) * NF + 2 * gg) = l2[li];
            }
        }
    }
    __syncthreads();                                     // sweep reads done before reuse

    // ---------------- chunk 1: t = 26..49 (72 floats/row) ----------------
    for (int s = 0; s < S1; ++s) {
        prev = rk_step(prev, xv, b, g);
        float* myrow = lds + lane * (S1 * 3);            // stride 72 now
        myrow[s * 3 + 0] = prev.s;
        myrow[s * 3 + 1] = prev.i;
        myrow[s * 3 + 2] = prev.r;
    }
    __syncthreads();

    {
        const float2* l2 = (const float2*)lds;
        const int per = S1 * 3 / 2;                      // 36 float2 per row
        const int total2 = nrows * per;
        for (int it = 0; it < per; ++it) {
            int li = it * ROWS + lane;
            if (li < total2) {
                int r  = li / per;
                int gg = li - r * per;
                // dst byte = 600*(row0+r) + 312 + 8*gg : 8B-aligned
                *reinterpret_cast<float2*>(
                    out + (size_t)(row0 + r) * NF + (S0 * 3) + 2 * gg) = l2[li];
            }
        }
    }
}

extern "C" void kernel_launch(void* const* d_in, const int* in_sizes, int n_in,
                              void* d_out, int out_size, void* d_ws, size_t ws_size,
                              hipStream_t stream) {
    const float* x     = (const float*)d_in[0];
    const float* beta  = (const float*)d_in[1];
    const float* gamma = (const float*)d_in[2];
    float* out = (float*)d_out;

    const int grid = (BATCH + ROWS - 1) / ROWS;          // 7813
    sir_rk4_kernel<<<grid, ROWS, 0, stream>>>(x, beta, gamma, out);
}